// Round 8
// baseline (182.518 us; speedup 1.0000x reference)
//
#include <hip/hip_runtime.h>
#include <hip/hip_bf16.h>
#include <stdint.h>

// Problem constants (fixed by setup_inputs)
#define NN 10000
#define EE 160000
#define BB 2
#define TT 12
#define FF 16
#define HG 32
#define HH 64
#define PP 4
#define BT (BB*TT)   // 24
#define MM (BB*NN)   // 20000
#define CAP 96       // fixed CSR capacity/node: deg ~ Binom(160k,1e-4), 20 sigma
#define L2E 1.4426950408889634f
#define LGRID 625    // lstmfc persistent grid: 2 tiles/block exactly (1250/625)

typedef _Float16 half8 __attribute__((ext_vector_type(8)));
typedef _Float16 h2 __attribute__((ext_vector_type(2)));
typedef float f32x4 __attribute__((ext_vector_type(4)));

union UP { uint32_t u; h2 h; };
union H8U { uint32_t u[4]; half8 v; };

// a pre-scaled by log2(e): sigmoid(x) = rcp(1 + exp2(-L*x))
__device__ __forceinline__ float sigm2(float a) {
  return __builtin_amdgcn_rcpf(1.0f + __builtin_amdgcn_exp2f(-a));
}
// a pre-scaled by 2*log2(e): tanh(x) = 1 - 2*rcp(1 + exp2(2L*x))
__device__ __forceinline__ float tanh2(float a) {
  return fmaf(-2.0f, __builtin_amdgcn_rcpf(1.0f + __builtin_amdgcn_exp2f(a)), 1.0f);
}
// g-gate: returns (2*L2E)*tanh(x); lets c be carried pre-scaled by 2*L2E.
__device__ __forceinline__ float tanh2g(float a) {
  return fmaf(-2.0f * (2.0f * L2E),
              __builtin_amdgcn_rcpf(1.0f + __builtin_amdgcn_exp2f(a)),
              2.0f * L2E);
}

// lgkm-only barrier (neutral vs __syncthreads per r2 A/B; never worse)
__device__ __forceinline__ void barrier_lds() {
  asm volatile("s_waitcnt lgkmcnt(0)" ::: "memory");
  __builtin_amdgcn_s_barrier();
  asm volatile("" ::: "memory");
}

// ---- merged: weight pre-pack (bid 0) + CSR build + era5 transpose ----
// Weight fold (r6/r7-proven): LSTM1 x-input =
//   (agg@Wg + gb)@w_ih1^T = agg @ (Wg@w_ih1^T) + (gb@w_ih1^T)
// -> Bxc = Wg@w_ih1^T packed as K=16 MFMA B-frags (k>=16 EXACT zeros) and
// gb@w_ih1^T folded into bias1.
// wbuf layout: dword e of thread t at wbuf[e*256+t] (lane-interleaved).
//   e 0..3 bias1c[g] | 4..7 bias2[g] | 8..11 wx[g]
//   e 12..27 Bxc[g] | 28..59 Bh1[g][c2] | 60..91 Bh2[g][c2]
#define FILL_BLKS (EE / 256)              // 625
#define PREP_BLKS ((NN * BT * 8) / 256)   // 7500
__global__ __launch_bounds__(256) void k_prepfill(
    const int* __restrict__ eidx, int* __restrict__ cnt, int* __restrict__ csr,
    const float* __restrict__ era5, uint32_t* __restrict__ xt,
    const float* __restrict__ gcn_w, const float* __restrict__ gcn_b,
    const float* __restrict__ w_ih1, const float* __restrict__ w_hh1,
    const float* __restrict__ b_ih1, const float* __restrict__ b_hh1,
    const float* __restrict__ w_ih2, const float* __restrict__ w_hh2,
    const float* __restrict__ b_ih2, const float* __restrict__ b_hh2,
    uint32_t* __restrict__ wbuf) {
  const int bid = blockIdx.x;
  const int tid = threadIdx.x;
  if (bid >= 1 && bid <= FILL_BLKS) {
    int e = (bid - 1) * 256 + tid;
    int d = eidx[EE + e];
    int pos = atomicAdd(&cnt[d], 1);
    if (pos < CAP) csr[d * CAP + pos] = eidx[e];
    return;
  }
  if (bid > FILL_BLKS) {
    int D = (bid - 1 - FILL_BLKS) * 256 + tid;  // dword index: xt[n][bt][fp]
    int f2 = D & 7;
    int bt = (D >> 3) % BT;
    int n = D / (8 * BT);
    const float* src = era5 + ((size_t)bt * NN + n) * FF + f2 * 2;
    UP u; u.h[0] = (_Float16)src[0]; u.h[1] = (_Float16)src[1];
    xt[D] = u.u;
    return;
  }
  // ---- bid 0: weight pre-pack ----
  __shared__ float wl[256 * HG];   // w_ih1, 32 KB
  __shared__ float gwl[FF * HG];   // gcn_w, 2 KB
  __shared__ float gbl[HG];
  for (int i = tid; i < 256 * HG; i += 256) wl[i] = w_ih1[i];
  for (int i = tid; i < FF * HG; i += 256) gwl[i] = gcn_w[i];
  if (tid < HG) gbl[tid] = gcn_b[tid];
  __syncthreads();

  const int wave = tid >> 6;
  const int lane = tid & 63;
  const int col = lane & 15;
  const int quad = lane >> 4;
#pragma unroll
  for (int g = 0; g < 4; ++g) {
    const float sc = (g == 2) ? 2.0f * L2E : L2E;
    int ncol = 16 * (wave + 4 * g) + col;
    const float* wr = &wl[ncol * HG];
    // combined bias: gb@w_ih1^T + b_ih1 + b_hh1
    float bc = 0.f;
    for (int hg = 0; hg < HG; ++hg) bc = fmaf(gbl[hg], wr[hg], bc);
    wbuf[(0 + g) * 256 + tid] =
        __float_as_uint((bc + b_ih1[ncol] + b_hh1[ncol]) * sc);
    wbuf[(4 + g) * 256 + tid] = __float_as_uint((b_ih2[ncol] + b_hh2[ncol]) * sc);
    wbuf[(8 + g) * 256 + tid] = __float_as_uint(w_ih2[ncol] * sc);
    // Bxc: B[k][ncol] = sum_hg gcn_w[k][hg]*w_ih1[ncol][hg]; k>=16 -> 0.0
    H8U bx;
#pragma unroll
    for (int j = 0; j < 8; ++j) {
      int k = quad * 8 + j;
      float v = 0.f;
      if (k < FF)
        for (int hg = 0; hg < HG; ++hg) v = fmaf(gwl[k * HG + hg], wr[hg], v);
      bx.v[j] = (_Float16)(v * sc);
    }
#pragma unroll
    for (int d = 0; d < 4; ++d) wbuf[(12 + g * 4 + d) * 256 + tid] = bx.u[d];
#pragma unroll
    for (int c2 = 0; c2 < 2; ++c2) {
      H8U b1, b2;
#pragma unroll
      for (int j = 0; j < 8; ++j) {
        b1.v[j] = (_Float16)(w_hh1[ncol * HH + c2 * 32 + quad * 8 + j] * sc);
        b2.v[j] = (_Float16)(w_hh2[ncol * HH + c2 * 32 + quad * 8 + j] * sc);
      }
#pragma unroll
      for (int d = 0; d < 4; ++d) {
        wbuf[(28 + (g * 2 + c2) * 4 + d) * 256 + tid] = b1.u[d];
        wbuf[(60 + (g * 2 + c2) * 4 + d) * 256 + tid] = b2.u[d];
      }
    }
  }
}

// ---- GCN aggregate on RAW features (768B/row); epilogue = normalize+store ----
__global__ __launch_bounds__(256) void k_gather(const uint32_t* __restrict__ xt,
                                                const int* __restrict__ csr,
                                                const int* __restrict__ cnt,
                                                uint32_t* __restrict__ agg) {
  const int tid = threadIdx.x;
  const int dloc = tid >> 6, lane = tid & 63;
  const int dst = blockIdx.x * 4 + dloc;
  const int cdst = min(cnt[dst], CAP);
  const float dinv_d = rsqrtf((float)cdst + 1.0f);

  float acc[6];
#pragma unroll
  for (int i = 0; i < 6; ++i) acc[i] = 0.f;

  for (int base = 0; base < cdst; base += 64) {
    int mine = base + lane;
    int sv = dst; float dvv = 0.f;   // padding: valid row, zero weight
    if (mine < cdst) {
      sv = csr[dst * CAP + mine];
      dvv = rsqrtf((float)cnt[sv] + 1.0f);
    }
    const int lim = min(64, cdst - base);
    for (int j = 0; j < lim; j += 4) {
      int sj[4]; float dj[4];
#pragma unroll
      for (int u = 0; u < 4; ++u) {
        int idx = j + u;
        sj[u] = __shfl(sv, idx);
        float d = __shfl(dvv, idx);
        dj[u] = (idx < lim) ? d : 0.f;
      }
      uint32_t dw[4][3];
#pragma unroll
      for (int u = 0; u < 4; ++u) {
        const uint32_t* row = xt + (size_t)sj[u] * 192;
#pragma unroll
        for (int k = 0; k < 3; ++k) dw[u][k] = row[lane + 64 * k];
      }
#pragma unroll
      for (int u = 0; u < 4; ++u) {
#pragma unroll
        for (int k = 0; k < 3; ++k) {
          UP up; up.u = dw[u][k];
          acc[2 * k]     = fmaf((float)up.h[0], dj[u], acc[2 * k]);
          acc[2 * k + 1] = fmaf((float)up.h[1], dj[u], acc[2 * k + 1]);
        }
      }
    }
  }
  // self term + symmetric normalization; store raw agg as f16 pairs
  const uint32_t* srow = xt + (size_t)dst * 192;
#pragma unroll
  for (int k = 0; k < 3; ++k) {
    UP u; u.u = srow[lane + 64 * k];
    int d0 = lane + 64 * k;
    int bt = d0 >> 3, fp = d0 & 7;
    int bb = (bt >= TT) ? 1 : 0;
    int t = bt - bb * TT;
    UP o;
    o.h[0] = (_Float16)((acc[2 * k]     + (float)u.h[0] * dinv_d) * dinv_d);
    o.h[1] = (_Float16)((acc[2 * k + 1] + (float)u.h[1] * dinv_d) * dinv_d);
    agg[((size_t)(bb * NN + dst) * TT + t) * 8 + fp] = o.u;
  }
}

// -------- fused dual LSTM + FC; PERSISTENT: grid 625, 2 tiles per block --------
// r3/r5/r7 counters: resident waves/CU = 0.27 x (total waves/256) regardless of
// block shape; concurrency never exceeds ~1.3 blocks/CU for the 1250-block
// launch although VGPR/LDS allow 4. Persistent form forces ~2.4 blocks/CU
// co-resident for the whole dispatch, amortizes the 92-dword weight prologue
// 2x, and removes the dispatch ramp. Per-tile body byte-identical to the
// proven 52us structure. No min-wave bound (r1 spill lesson).
__global__ __launch_bounds__(256) void k_lstmfc(
    const _Float16* __restrict__ agg, const float* __restrict__ zeta,
    const uint32_t* __restrict__ wbuf,
    const float* __restrict__ fc_w, const float* __restrict__ fc_b,
    float* __restrict__ out) {
  const int tid = threadIdx.x;
  const int wave = tid >> 6;
  const int lane = tid & 63;
  const int col = lane & 15;
  const int quad = lane >> 4;

  // coalesced weight prologue: 92 dword loads, ONCE per block (2 tiles)
  float bias1[4], bias2[4], wx[4];
  H8U Bx[4], Bh1[4][2], Bh2[4][2];
#pragma unroll
  for (int g = 0; g < 4; ++g) {
    bias1[g] = __uint_as_float(wbuf[(0 + g) * 256 + tid]);
    bias2[g] = __uint_as_float(wbuf[(4 + g) * 256 + tid]);
    wx[g]    = __uint_as_float(wbuf[(8 + g) * 256 + tid]);
#pragma unroll
    for (int d = 0; d < 4; ++d) Bx[g].u[d] = wbuf[(12 + g * 4 + d) * 256 + tid];
#pragma unroll
    for (int c2 = 0; c2 < 2; ++c2)
#pragma unroll
      for (int d = 0; d < 4; ++d) {
        Bh1[g][c2].u[d] = wbuf[(28 + (g * 2 + c2) * 4 + d) * 256 + tid];
        Bh2[g][c2].u[d] = wbuf[(60 + (g * 2 + c2) * 4 + d) * 256 + tid];
      }
  }
  // loop-invariant MFMA C-operand bias vectors
  f32x4 bv1[4];
#pragma unroll
  for (int g = 0; g < 4; ++g) {
    f32x4 v = {bias1[g], bias1[g], bias1[g], bias1[g]};
    bv1[g] = v;
  }

  // LDS: h-exchange double-buffers aliased with FC buffer (disjoint in time)
  __shared__ union {
    struct {
      __align__(16) _Float16 hb1[2][16 * 72];
      __align__(16) _Float16 hb2[2][16 * 72];
    } h;                       // 9216 B
    float fcb[16][132];        // 8448 B
  } su;
  __shared__ float zbuf[TT][16];

#pragma unroll 1
  for (int tile = blockIdx.x; tile < MM / 16; tile += LGRID) {
    const int m0 = tile * 16;
    const int b = (m0 >= NN) ? 1 : 0;
    const int n0 = m0 - b * NN;

    // tile boundary: prev tile's fcb reads done before zbuf/hb reuse
    barrier_lds();
    if (tid < TT * 16) {
      int t = tid >> 4, s = tid & 15;
      zbuf[t][s] = zeta[((size_t)b * TT + t) * NN + n0 + s];
    }
    // agg row for node (m0+col): [12 t][16 f] f16; quads 2-3 mirror 0-1
    // (Bxc rows k>=16 are exact zeros -> mirrored data multiplies to 0)
    const _Float16* gbase =
        agg + (size_t)(m0 + col) * (TT * FF) + (quad & 1) * 8;
    half8 A0 = *(const half8*)(gbase);

    // cell state carried pre-scaled by 2*L2E (see tanh2g)
    float c1[4] = {0.f, 0.f, 0.f, 0.f}, c2v[4] = {0.f, 0.f, 0.f, 0.f};
    float h1f[4], h2f[4];

    barrier_lds();   // zbuf visible; A0 prefetch stays in flight

#pragma unroll
    for (int t = 0; t < TT; ++t) {
      const int p = t & 1;
      if (t > 0) {
#pragma unroll
        for (int r = 0; r < 4; ++r) {
          int a = (quad * 4 + r) * 72 + 16 * wave + col;
          su.h.hb1[p][a] = (_Float16)h1f[r];
          su.h.hb2[p][a] = (_Float16)h2f[r];
        }
      }
      f32x4 a1[4], a2[4];
      const f32x4 z4 = *(const f32x4*)(&zbuf[t][quad * 4]);
#pragma unroll
      for (int g = 0; g < 4; ++g) {
        a1[g] = __builtin_amdgcn_mfma_f32_16x16x32_f16(A0, Bx[g].v, bv1[g], 0, 0, 0);
#pragma unroll
        for (int r = 0; r < 4; ++r)
          a2[g][r] = fmaf(wx[g], z4[r], bias2[g]);
      }
      if (t < TT - 1) A0 = *(const half8*)(gbase + (t + 1) * FF);
      if (t > 0) {
        barrier_lds();
        const half8 A11 = *(const half8*)(&su.h.hb1[p][col * 72 + quad * 8]);
        const half8 A21 = *(const half8*)(&su.h.hb1[p][col * 72 + 32 + quad * 8]);
        const half8 A12 = *(const half8*)(&su.h.hb2[p][col * 72 + quad * 8]);
        const half8 A22 = *(const half8*)(&su.h.hb2[p][col * 72 + 32 + quad * 8]);
#pragma unroll
        for (int g = 0; g < 4; ++g) {
          a1[g] = __builtin_amdgcn_mfma_f32_16x16x32_f16(A11, Bh1[g][0].v, a1[g], 0, 0, 0);
          a1[g] = __builtin_amdgcn_mfma_f32_16x16x32_f16(A21, Bh1[g][1].v, a1[g], 0, 0, 0);
          a2[g] = __builtin_amdgcn_mfma_f32_16x16x32_f16(A12, Bh2[g][0].v, a2[g], 0, 0, 0);
          a2[g] = __builtin_amdgcn_mfma_f32_16x16x32_f16(A22, Bh2[g][1].v, a2[g], 0, 0, 0);
        }
      }
#pragma unroll
      for (int r = 0; r < 4; ++r) {
        float i1 = sigm2(a1[0][r]), f1 = sigm2(a1[1][r]);
        float g1 = tanh2g(a1[2][r]), o1 = sigm2(a1[3][r]);
        c1[r] = fmaf(f1, c1[r], i1 * g1);
        h1f[r] = o1 * tanh2(c1[r]);
        float i2 = sigm2(a2[0][r]), f2 = sigm2(a2[1][r]);
        float g2 = tanh2g(a2[2][r]), o2 = sigm2(a2[3][r]);
        c2v[r] = fmaf(f2, c2v[r], i2 * g2);
        h2f[r] = o2 * tanh2(c2v[r]);
      }
    }
    // alias hazard: all waves finish their last hb reads before fcb writes
    barrier_lds();
#pragma unroll
    for (int r = 0; r < 4; ++r) {
      su.fcb[quad * 4 + r][16 * wave + col] = h1f[r];
      su.fcb[quad * 4 + r][64 + 16 * wave + col] = h2f[r];
    }
    barrier_lds();
    if (tid < 64) {
      int pp = tid >> 4, s = tid & 15;
      const f32x4* wr = (const f32x4*)(fc_w + pp * 128);
      const float* hv = su.fcb[s];
      float acc = fc_b[pp];
#pragma unroll
      for (int k = 0; k < 32; ++k) {
        f32x4 w4 = wr[k];
        acc += w4[0] * hv[4 * k] + w4[1] * hv[4 * k + 1] +
               w4[2] * hv[4 * k + 2] + w4[3] * hv[4 * k + 3];
      }
      out[((size_t)(b * PP + pp)) * NN + n0 + s] = acc;
    }
  }
}

extern "C" void kernel_launch(void* const* d_in, const int* in_sizes, int n_in,
                              void* d_out, int out_size, void* d_ws, size_t ws_size,
                              hipStream_t stream) {
  (void)in_sizes; (void)n_in; (void)out_size; (void)ws_size;
  const float* era5  = (const float*)d_in[0];
  const float* zeta  = (const float*)d_in[1];
  const int*   eidx  = (const int*)d_in[2];
  const float* gcn_w = (const float*)d_in[3];
  const float* gcn_b = (const float*)d_in[4];
  const float* w_ih1 = (const float*)d_in[5];
  const float* w_hh1 = (const float*)d_in[6];
  const float* b_ih1 = (const float*)d_in[7];
  const float* b_hh1 = (const float*)d_in[8];
  const float* w_ih2 = (const float*)d_in[9];
  const float* w_hh2 = (const float*)d_in[10];
  const float* b_ih2 = (const float*)d_in[11];
  const float* b_hh2 = (const float*)d_in[12];
  const float* fc_w  = (const float*)d_in[13];
  const float* fc_b  = (const float*)d_in[14];
  float* out = (float*)d_out;

  // compact workspace: ~20.1 MB span
  char* ws = (char*)d_ws;
  int*      cnt  = (int*)(ws);                        // 40 KB
  int*      csr  = (int*)(ws + (64 << 10));           // 3.84 MB
  uint32_t* xt   = (uint32_t*)(ws + (4ull << 20));    // [N][BT][8] fp16, 7.68 MB
  uint32_t* agg  = (uint32_t*)(ws + (12ull << 20));   // [M][T][8] fp16, 7.68 MB
  uint32_t* wbuf = (uint32_t*)(ws + (20ull << 20));   // 92*256*4 = 94 KB

  hipMemsetAsync(cnt, 0, NN * sizeof(int), stream);
  k_prepfill<<<1 + FILL_BLKS + PREP_BLKS, 256, 0, stream>>>(
      eidx, cnt, csr, era5, xt, gcn_w, gcn_b,
      w_ih1, w_hh1, b_ih1, b_hh1, w_ih2, w_hh2, b_ih2, b_hh2, wbuf);
  k_gather<<<NN / 4, 256, 0, stream>>>(xt, csr, cnt, agg);
  k_lstmfc<<<LGRID, 256, 0, stream>>>((const _Float16*)agg, zeta, wbuf,
                                      fc_w, fc_b, out);
}

// Round 9
// 167.375 us; speedup vs baseline: 1.0905x; 1.0905x over previous
//
#include <hip/hip_runtime.h>
#include <hip/hip_bf16.h>
#include <stdint.h>

// Problem constants (fixed by setup_inputs)
#define NN 10000
#define EE 160000
#define BB 2
#define TT 12
#define FF 16
#define HG 32
#define HH 64
#define PP 4
#define BT (BB*TT)   // 24
#define MM (BB*NN)   // 20000
#define CAP 96       // fixed CSR capacity/node: deg ~ Binom(160k,1e-4), 20 sigma
#define L2E 1.4426950408889634f

typedef _Float16 half8 __attribute__((ext_vector_type(8)));
typedef _Float16 h2 __attribute__((ext_vector_type(2)));
typedef float f32x4 __attribute__((ext_vector_type(4)));
typedef int i32x4 __attribute__((ext_vector_type(4)));
typedef uint32_t u32x2 __attribute__((ext_vector_type(2)));

union UP { uint32_t u; h2 h; };
union H8U { uint32_t u[4]; half8 v; };

// a pre-scaled by log2(e): sigmoid(x) = rcp(1 + exp2(-L*x))
__device__ __forceinline__ float sigm2(float a) {
  return __builtin_amdgcn_rcpf(1.0f + __builtin_amdgcn_exp2f(-a));
}
// a pre-scaled by 2*log2(e): tanh(x) = 1 - 2*rcp(1 + exp2(2L*x))
__device__ __forceinline__ float tanh2(float a) {
  return fmaf(-2.0f, __builtin_amdgcn_rcpf(1.0f + __builtin_amdgcn_exp2f(a)), 1.0f);
}
// g-gate: returns (2*L2E)*tanh(x); lets c be carried pre-scaled by 2*L2E.
__device__ __forceinline__ float tanh2g(float a) {
  return fmaf(-2.0f * (2.0f * L2E),
              __builtin_amdgcn_rcpf(1.0f + __builtin_amdgcn_exp2f(a)),
              2.0f * L2E);
}

// lgkm-only barrier (neutral vs __syncthreads per r2 A/B; never worse)
__device__ __forceinline__ void barrier_lds() {
  asm volatile("s_waitcnt lgkmcnt(0)" ::: "memory");
  __builtin_amdgcn_s_barrier();
  asm volatile("" ::: "memory");
}

// ---- merged: weight pre-pack (bid 0) + CSR build + era5 transpose ----
// r8 ledger: prepfill was 8126 blocks x ~1 dword/thread — thousands of
// near-empty workgroups hiding a dispatch-bound tail below the top-5 cutoff.
// Restructured to 1096 fat blocks: fill = 157 blocks x int4 edges, transpose =
// 938 blocks x 4 iterations of float4-read/uint2-write per thread. Access
// patterns per iteration unchanged (reads 64B-coalesced, writes coalesced).
// Weight fold (r6/r7-proven): Bxc = Wg@w_ih1^T (K=16 frags, k>=16 exact 0),
// gb@w_ih1^T folded into bias1.
// wbuf layout: dword e of thread t at wbuf[e*256+t] (lane-interleaved).
//   e 0..3 bias1c[g] | 4..7 bias2[g] | 8..11 wx[g]
//   e 12..27 Bxc[g] | 28..59 Bh1[g][c2] | 60..91 Bh2[g][c2]
#define FILL_BLKS 157                     // ceil(160000 / (256*4))
#define PREP_BLKS 938                     // ceil(1920000 dwords / (256*8))
#define PREP_STRIDE (PREP_BLKS * 256)     // 240128 threads
__global__ __launch_bounds__(256) void k_prepfill(
    const int* __restrict__ eidx, int* __restrict__ cnt, int* __restrict__ csr,
    const float* __restrict__ era5, uint32_t* __restrict__ xt,
    const float* __restrict__ gcn_w, const float* __restrict__ gcn_b,
    const float* __restrict__ w_ih1, const float* __restrict__ w_hh1,
    const float* __restrict__ b_ih1, const float* __restrict__ b_hh1,
    const float* __restrict__ w_ih2, const float* __restrict__ w_hh2,
    const float* __restrict__ b_ih2, const float* __restrict__ b_hh2,
    uint32_t* __restrict__ wbuf) {
  const int bid = blockIdx.x;
  const int tid = threadIdx.x;
  if (bid >= 1 && bid <= FILL_BLKS) {
    // 4 edges per thread via int4 (aligned: EE*4B and e4*4B are 16B multiples)
    int e4 = ((bid - 1) * 256 + tid) * 4;
    if (e4 < EE) {
      i32x4 d4 = *(const i32x4*)&eidx[EE + e4];
      i32x4 s4 = *(const i32x4*)&eidx[e4];
#pragma unroll
      for (int u = 0; u < 4; ++u) {
        int e = e4 + u;
        if (e < EE) {
          int pos = atomicAdd(&cnt[d4[u]], 1);
          if (pos < CAP) csr[d4[u] * CAP + pos] = s4[u];
        }
      }
    }
    return;
  }
  if (bid > FILL_BLKS) {
    // transpose era5[bt][n][f] f32 -> xt[n][bt][fp] f16-pairs.
    // Each thread: 4 grid-strided dword-PAIRS (read float4 / write uint2).
    const int base = (bid - 1 - FILL_BLKS) * 256 + tid;
#pragma unroll
    for (int i = 0; i < 4; ++i) {
      int P = base + i * PREP_STRIDE;        // pair index
      if (P < NN * BT * 4) {
        int D = P * 2;                       // dword index: xt[n][bt][fp]
        int fp = D & 7;                      // even (0,2,4,6)
        int bt = (D >> 3) % BT;
        int n = D / (8 * BT);
        const f32x4 s = *(const f32x4*)(era5 + ((size_t)bt * NN + n) * FF + fp * 2);
        UP u0, u1;
        u0.h[0] = (_Float16)s[0]; u0.h[1] = (_Float16)s[1];
        u1.h[0] = (_Float16)s[2]; u1.h[1] = (_Float16)s[3];
        u32x2 w; w[0] = u0.u; w[1] = u1.u;
        *(u32x2*)&xt[D] = w;
      }
    }
    return;
  }
  // ---- bid 0: weight pre-pack ----
  __shared__ float wl[256 * HG];   // w_ih1, 32 KB
  __shared__ float gwl[FF * HG];   // gcn_w, 2 KB
  __shared__ float gbl[HG];
  for (int i = tid; i < 256 * HG; i += 256) wl[i] = w_ih1[i];
  for (int i = tid; i < FF * HG; i += 256) gwl[i] = gcn_w[i];
  if (tid < HG) gbl[tid] = gcn_b[tid];
  __syncthreads();

  const int wave = tid >> 6;
  const int lane = tid & 63;
  const int col = lane & 15;
  const int quad = lane >> 4;
#pragma unroll
  for (int g = 0; g < 4; ++g) {
    const float sc = (g == 2) ? 2.0f * L2E : L2E;
    int ncol = 16 * (wave + 4 * g) + col;
    const float* wr = &wl[ncol * HG];
    // combined bias: gb@w_ih1^T + b_ih1 + b_hh1
    float bc = 0.f;
    for (int hg = 0; hg < HG; ++hg) bc = fmaf(gbl[hg], wr[hg], bc);
    wbuf[(0 + g) * 256 + tid] =
        __float_as_uint((bc + b_ih1[ncol] + b_hh1[ncol]) * sc);
    wbuf[(4 + g) * 256 + tid] = __float_as_uint((b_ih2[ncol] + b_hh2[ncol]) * sc);
    wbuf[(8 + g) * 256 + tid] = __float_as_uint(w_ih2[ncol] * sc);
    // Bxc: B[k][ncol] = sum_hg gcn_w[k][hg]*w_ih1[ncol][hg]; k>=16 -> 0.0
    H8U bx;
#pragma unroll
    for (int j = 0; j < 8; ++j) {
      int k = quad * 8 + j;
      float v = 0.f;
      if (k < FF)
        for (int hg = 0; hg < HG; ++hg) v = fmaf(gwl[k * HG + hg], wr[hg], v);
      bx.v[j] = (_Float16)(v * sc);
    }
#pragma unroll
    for (int d = 0; d < 4; ++d) wbuf[(12 + g * 4 + d) * 256 + tid] = bx.u[d];
#pragma unroll
    for (int c2 = 0; c2 < 2; ++c2) {
      H8U b1, b2;
#pragma unroll
      for (int j = 0; j < 8; ++j) {
        b1.v[j] = (_Float16)(w_hh1[ncol * HH + c2 * 32 + quad * 8 + j] * sc);
        b2.v[j] = (_Float16)(w_hh2[ncol * HH + c2 * 32 + quad * 8 + j] * sc);
      }
#pragma unroll
      for (int d = 0; d < 4; ++d) {
        wbuf[(28 + (g * 2 + c2) * 4 + d) * 256 + tid] = b1.u[d];
        wbuf[(60 + (g * 2 + c2) * 4 + d) * 256 + tid] = b2.u[d];
      }
    }
  }
}

// ---- GCN aggregate on RAW features (768B/row); epilogue = normalize+store ----
// (byte-identical to r7)
__global__ __launch_bounds__(256) void k_gather(const uint32_t* __restrict__ xt,
                                                const int* __restrict__ csr,
                                                const int* __restrict__ cnt,
                                                uint32_t* __restrict__ agg) {
  const int tid = threadIdx.x;
  const int dloc = tid >> 6, lane = tid & 63;
  const int dst = blockIdx.x * 4 + dloc;
  const int cdst = min(cnt[dst], CAP);
  const float dinv_d = rsqrtf((float)cdst + 1.0f);

  float acc[6];
#pragma unroll
  for (int i = 0; i < 6; ++i) acc[i] = 0.f;

  for (int base = 0; base < cdst; base += 64) {
    int mine = base + lane;
    int sv = dst; float dvv = 0.f;   // padding: valid row, zero weight
    if (mine < cdst) {
      sv = csr[dst * CAP + mine];
      dvv = rsqrtf((float)cnt[sv] + 1.0f);
    }
    const int lim = min(64, cdst - base);
    for (int j = 0; j < lim; j += 4) {
      int sj[4]; float dj[4];
#pragma unroll
      for (int u = 0; u < 4; ++u) {
        int idx = j + u;
        sj[u] = __shfl(sv, idx);
        float d = __shfl(dvv, idx);
        dj[u] = (idx < lim) ? d : 0.f;
      }
      uint32_t dw[4][3];
#pragma unroll
      for (int u = 0; u < 4; ++u) {
        const uint32_t* row = xt + (size_t)sj[u] * 192;
#pragma unroll
        for (int k = 0; k < 3; ++k) dw[u][k] = row[lane + 64 * k];
      }
#pragma unroll
      for (int u = 0; u < 4; ++u) {
#pragma unroll
        for (int k = 0; k < 3; ++k) {
          UP up; up.u = dw[u][k];
          acc[2 * k]     = fmaf((float)up.h[0], dj[u], acc[2 * k]);
          acc[2 * k + 1] = fmaf((float)up.h[1], dj[u], acc[2 * k + 1]);
        }
      }
    }
  }
  // self term + symmetric normalization; store raw agg as f16 pairs
  const uint32_t* srow = xt + (size_t)dst * 192;
#pragma unroll
  for (int k = 0; k < 3; ++k) {
    UP u; u.u = srow[lane + 64 * k];
    int d0 = lane + 64 * k;
    int bt = d0 >> 3, fp = d0 & 7;
    int bb = (bt >= TT) ? 1 : 0;
    int t = bt - bb * TT;
    UP o;
    o.h[0] = (_Float16)((acc[2 * k]     + (float)u.h[0] * dinv_d) * dinv_d);
    o.h[1] = (_Float16)((acc[2 * k + 1] + (float)u.h[1] * dinv_d) * dinv_d);
    agg[((size_t)(bb * NN + dst) * TT + t) * 8 + fp] = o.u;
  }
}

// -------- fused dual LSTM + FC; r7's proven 52us body (byte-identical) --------
__global__ __launch_bounds__(256) void k_lstmfc(
    const _Float16* __restrict__ agg, const float* __restrict__ zeta,
    const uint32_t* __restrict__ wbuf,
    const float* __restrict__ fc_w, const float* __restrict__ fc_b,
    float* __restrict__ out) {
  const int m0 = blockIdx.x * 16;
  const int b = (m0 >= NN) ? 1 : 0;
  const int n0 = m0 - b * NN;
  const int tid = threadIdx.x;
  const int wave = tid >> 6;
  const int lane = tid & 63;
  const int col = lane & 15;
  const int quad = lane >> 4;

  // coalesced prologue: 92 dword loads, zero VALU
  float bias1[4], bias2[4], wx[4];
  H8U Bx[4], Bh1[4][2], Bh2[4][2];
#pragma unroll
  for (int g = 0; g < 4; ++g) {
    bias1[g] = __uint_as_float(wbuf[(0 + g) * 256 + tid]);
    bias2[g] = __uint_as_float(wbuf[(4 + g) * 256 + tid]);
    wx[g]    = __uint_as_float(wbuf[(8 + g) * 256 + tid]);
#pragma unroll
    for (int d = 0; d < 4; ++d) Bx[g].u[d] = wbuf[(12 + g * 4 + d) * 256 + tid];
#pragma unroll
    for (int c2 = 0; c2 < 2; ++c2)
#pragma unroll
      for (int d = 0; d < 4; ++d) {
        Bh1[g][c2].u[d] = wbuf[(28 + (g * 2 + c2) * 4 + d) * 256 + tid];
        Bh2[g][c2].u[d] = wbuf[(60 + (g * 2 + c2) * 4 + d) * 256 + tid];
      }
  }
  // loop-invariant MFMA C-operand bias vectors
  f32x4 bv1[4];
#pragma unroll
  for (int g = 0; g < 4; ++g) {
    f32x4 v = {bias1[g], bias1[g], bias1[g], bias1[g]};
    bv1[g] = v;
  }

  // LDS: h-exchange double-buffers aliased with FC buffer (disjoint in time)
  __shared__ union {
    struct {
      __align__(16) _Float16 hb1[2][16 * 72];
      __align__(16) _Float16 hb2[2][16 * 72];
    } h;                       // 9216 B
    float fcb[16][132];        // 8448 B
  } su;
  __shared__ float zbuf[TT][16];

  if (tid < TT * 16) {
    int t = tid >> 4, s = tid & 15;
    zbuf[t][s] = zeta[((size_t)b * TT + t) * NN + n0 + s];
  }

  // agg row for node (m0+col): [12 t][16 f] f16; quads 2-3 mirror 0-1
  // (Bxc rows k>=16 are exact zeros -> mirrored data multiplies to 0)
  const _Float16* gbase =
      agg + (size_t)(m0 + col) * (TT * FF) + (quad & 1) * 8;
  half8 A0 = *(const half8*)(gbase);

  // cell state carried pre-scaled by 2*L2E (see tanh2g)
  float c1[4] = {0.f, 0.f, 0.f, 0.f}, c2v[4] = {0.f, 0.f, 0.f, 0.f};
  float h1f[4], h2f[4];

  barrier_lds();   // zbuf visible; A0/weight prefetches stay in flight

#pragma unroll
  for (int t = 0; t < TT; ++t) {
    const int p = t & 1;
    if (t > 0) {
#pragma unroll
      for (int r = 0; r < 4; ++r) {
        int a = (quad * 4 + r) * 72 + 16 * wave + col;
        su.h.hb1[p][a] = (_Float16)h1f[r];
        su.h.hb2[p][a] = (_Float16)h2f[r];
      }
    }
    f32x4 a1[4], a2[4];
    const f32x4 z4 = *(const f32x4*)(&zbuf[t][quad * 4]);
#pragma unroll
    for (int g = 0; g < 4; ++g) {
      a1[g] = __builtin_amdgcn_mfma_f32_16x16x32_f16(A0, Bx[g].v, bv1[g], 0, 0, 0);
#pragma unroll
      for (int r = 0; r < 4; ++r)
        a2[g][r] = fmaf(wx[g], z4[r], bias2[g]);
    }
    if (t < TT - 1) A0 = *(const half8*)(gbase + (t + 1) * FF);
    if (t > 0) {
      barrier_lds();
      const half8 A11 = *(const half8*)(&su.h.hb1[p][col * 72 + quad * 8]);
      const half8 A21 = *(const half8*)(&su.h.hb1[p][col * 72 + 32 + quad * 8]);
      const half8 A12 = *(const half8*)(&su.h.hb2[p][col * 72 + quad * 8]);
      const half8 A22 = *(const half8*)(&su.h.hb2[p][col * 72 + 32 + quad * 8]);
#pragma unroll
      for (int g = 0; g < 4; ++g) {
        a1[g] = __builtin_amdgcn_mfma_f32_16x16x32_f16(A11, Bh1[g][0].v, a1[g], 0, 0, 0);
        a1[g] = __builtin_amdgcn_mfma_f32_16x16x32_f16(A21, Bh1[g][1].v, a1[g], 0, 0, 0);
        a2[g] = __builtin_amdgcn_mfma_f32_16x16x32_f16(A12, Bh2[g][0].v, a2[g], 0, 0, 0);
        a2[g] = __builtin_amdgcn_mfma_f32_16x16x32_f16(A22, Bh2[g][1].v, a2[g], 0, 0, 0);
      }
    }
#pragma unroll
    for (int r = 0; r < 4; ++r) {
      float i1 = sigm2(a1[0][r]), f1 = sigm2(a1[1][r]);
      float g1 = tanh2g(a1[2][r]), o1 = sigm2(a1[3][r]);
      c1[r] = fmaf(f1, c1[r], i1 * g1);
      h1f[r] = o1 * tanh2(c1[r]);
      float i2 = sigm2(a2[0][r]), f2 = sigm2(a2[1][r]);
      float g2 = tanh2g(a2[2][r]), o2 = sigm2(a2[3][r]);
      c2v[r] = fmaf(f2, c2v[r], i2 * g2);
      h2f[r] = o2 * tanh2(c2v[r]);
    }
  }
  // alias hazard: all waves must finish their last hb reads before fcb writes
  barrier_lds();
#pragma unroll
  for (int r = 0; r < 4; ++r) {
    su.fcb[quad * 4 + r][16 * wave + col] = h1f[r];
    su.fcb[quad * 4 + r][64 + 16 * wave + col] = h2f[r];
  }
  barrier_lds();
  if (tid < 64) {
    int pp = tid >> 4, s = tid & 15;
    const f32x4* wr = (const f32x4*)(fc_w + pp * 128);
    const float* hv = su.fcb[s];
    float acc = fc_b[pp];
#pragma unroll
    for (int k = 0; k < 32; ++k) {
      f32x4 w4 = wr[k];
      acc += w4[0] * hv[4 * k] + w4[1] * hv[4 * k + 1] +
             w4[2] * hv[4 * k + 2] + w4[3] * hv[4 * k + 3];
    }
    out[((size_t)(b * PP + pp)) * NN + n0 + s] = acc;
  }
}

extern "C" void kernel_launch(void* const* d_in, const int* in_sizes, int n_in,
                              void* d_out, int out_size, void* d_ws, size_t ws_size,
                              hipStream_t stream) {
  (void)in_sizes; (void)n_in; (void)out_size; (void)ws_size;
  const float* era5  = (const float*)d_in[0];
  const float* zeta  = (const float*)d_in[1];
  const int*   eidx  = (const int*)d_in[2];
  const float* gcn_w = (const float*)d_in[3];
  const float* gcn_b = (const float*)d_in[4];
  const float* w_ih1 = (const float*)d_in[5];
  const float* w_hh1 = (const float*)d_in[6];
  const float* b_ih1 = (const float*)d_in[7];
  const float* b_hh1 = (const float*)d_in[8];
  const float* w_ih2 = (const float*)d_in[9];
  const float* w_hh2 = (const float*)d_in[10];
  const float* b_ih2 = (const float*)d_in[11];
  const float* b_hh2 = (const float*)d_in[12];
  const float* fc_w  = (const float*)d_in[13];
  const float* fc_b  = (const float*)d_in[14];
  float* out = (float*)d_out;

  // compact workspace: ~20.1 MB span
  char* ws = (char*)d_ws;
  int*      cnt  = (int*)(ws);                        // 40 KB
  int*      csr  = (int*)(ws + (64 << 10));           // 3.84 MB
  uint32_t* xt   = (uint32_t*)(ws + (4ull << 20));    // [N][BT][8] fp16, 7.68 MB
  uint32_t* agg  = (uint32_t*)(ws + (12ull << 20));   // [M][T][8] fp16, 7.68 MB
  uint32_t* wbuf = (uint32_t*)(ws + (20ull << 20));   // 92*256*4 = 94 KB

  hipMemsetAsync(cnt, 0, NN * sizeof(int), stream);
  k_prepfill<<<1 + FILL_BLKS + PREP_BLKS, 256, 0, stream>>>(
      eidx, cnt, csr, era5, xt, gcn_w, gcn_b,
      w_ih1, w_hh1, b_ih1, b_hh1, w_ih2, w_hh2, b_ih2, b_hh2, wbuf);
  k_gather<<<NN / 4, 256, 0, stream>>>(xt, csr, cnt, agg);
  k_lstmfc<<<MM / 16, 256, 0, stream>>>((const _Float16*)agg, zeta, wbuf,
                                        fc_w, fc_b, out);
}